// Round 15
// baseline (12507.324 us; speedup 1.0000x reference)
//
#include <hip/hip_runtime.h>
#include <cstdint>
#include <cstddef>

typedef _Float16 f16;
typedef _Float16 f16x4 __attribute__((ext_vector_type(4)));
typedef _Float16 f16x8 __attribute__((ext_vector_type(8)));
typedef float f32x4 __attribute__((ext_vector_type(4)));

// ---------- sizes ----------
#define SEQ 1024
#define BATCH 128
#define INDIM 256
#define HDIM 512
#define MROWS (SEQ * BATCH)          // 131072
#define NCOLS (3 * HDIM)             // 1536
#define BHDIM (BATCH * HDIM)         // 65536
#define TCHUNK 256
#define CHROWS (TCHUNK * BATCH)      // 32768
#define NCH (SEQ / TCHUNK)           // 4

// workspace layout (bytes); total 473,176,064 < 506,730,496 proven available
#define P32_OFF   0ull                         // [32768][1536] f32 = 201,326,592
#define Y0_OFF    201326592ull                 // [131072][512] f32 = 268,435,456
#define WHI_OFF   469762048ull                 // [1536][512] f16   = 1,572,864
#define WLO_OFF   471334912ull                 // [1536][512] f16   = 1,572,864
#define BIAS_OFF  472907776ull                 // [1536] f32        = 6,144
#define HST_OFF   472913920ull                 // [65536] f32       = 262,144
#define WS_NEEDED 473176064ull

__device__ __forceinline__ float fast_tanh(float x) {
  return 1.0f - 2.0f / (__expf(2.0f * x) + 1.0f);
}
__device__ __forceinline__ float fast_sigmoid(float x) {
  return 1.0f / (1.0f + __expf(-x));
}

__device__ __forceinline__ void split4(const float* __restrict__ in, f16* __restrict__ hi,
                                       f16* __restrict__ lo, int i) {
  float4 v = reinterpret_cast<const float4*>(in)[i];
  f16x4 h4 = {(f16)v.x, (f16)v.y, (f16)v.z, (f16)v.w};
  f16x4 l4 = {(f16)((v.x - (float)h4[0]) * 2048.0f),
              (f16)((v.y - (float)h4[1]) * 2048.0f),
              (f16)((v.z - (float)h4[2]) * 2048.0f),
              (f16)((v.w - (float)h4[3]) * 2048.0f)};
  reinterpret_cast<f16x4*>(hi)[i] = h4;
  reinterpret_cast<f16x4*>(lo)[i] = l4;
}

// ---------- consolidated prep: 3 weight splits + 3 bias copies (one dispatch) ----------
__global__ __launch_bounds__(256) void prep_kernel(
    const float* __restrict__ w0, const float* __restrict__ w1, const float* __restrict__ w2,
    f16* __restrict__ wh, f16* __restrict__ wl, int n4w,
    const float* __restrict__ b0, const float* __restrict__ b1, const float* __restrict__ b2,
    float* __restrict__ bias, int nb4) {
  const int total = 3 * n4w + 3 * nb4;
  const int stride = gridDim.x * blockDim.x;
  for (int i = blockIdx.x * blockDim.x + threadIdx.x; i < total; i += stride) {
    if (i < 3 * n4w) {
      int m = i / n4w;
      int off = i - m * n4w;
      const float* src = (m == 0) ? w0 : ((m == 1) ? w1 : w2);
      split4(src, wh + (long)m * n4w * 4, wl + (long)m * n4w * 4, off);
    } else {
      int k = i - 3 * n4w;
      int m = k / nb4;
      int off = k - m * nb4;
      const float* src = (m == 0) ? b0 : ((m == 1) ? b1 : b2);
      reinterpret_cast<float4*>(bias)[m * nb4 + off] =
          reinterpret_cast<const float4*>(src)[off];
    }
  }
}

// ---------- GEMM: P[CHROWS,1536](f32) = (split(A_f32)).(Whi+Wlo/2048)^T + bias ----------
// r13 structure with SINGLE-buffered LDS (registers already hold tile t+1 during
// compute of t — the LDS double-buffer was redundant). 40KB/block -> 4 blocks/CU
// = 16 waves/CU (r13: 80KB -> 2 blocks -> 8 waves, per-wave-issue-bound at 2/SIMD).
// 2 barriers/K-step now, covered by 4 INDEPENDENT blocks per CU (TLP).
// Global patterns = r13 (proven best coalescing: 128B row segments).
__global__ __launch_bounds__(256, 4) void gemm_split_kernel(
    const float* __restrict__ A,
    const f16* __restrict__ Whi, const f16* __restrict__ Wlo,
    const float* __restrict__ bias, float* __restrict__ P, int K) {
  constexpr int BK = 32;
  constexpr int LDSS = BK + 8;  // 40 f16 = 80 B row stride (uniform read banks)
  __shared__ f16 sAh[128 * LDSS];
  __shared__ f16 sAl[128 * LDSS];
  __shared__ f16 sBh[128 * LDSS];
  __shared__ f16 sBl[128 * LDSS];

  const int tid = threadIdx.x;
  const int lane = tid & 63;
  const int w = tid >> 6;
  const int wm = (w >> 1) * 64;
  const int wn = (w & 1) * 64;

  // XCD-aware bijective swizzle (gridDim.x = 3072, %8 == 0), n-block fastest
  const int per = gridDim.x >> 3;
  const int logical = (blockIdx.x & 7) * per + (blockIdx.x >> 3);
  const int nb = logical % (NCOLS / 128);
  const int mb = logical / (NCOLS / 128);
  const long m0 = (long)mb * 128;
  const int n0 = nb * 128;

  const int fr = lane & 15;
  const int fk = (lane >> 4) * 8;

  // A staging: 128x32 f32 tile = 4 rounds x 256 threads x 16B (float4); 128B/row segs.
  const int arow = tid >> 3;
  const int ac4 = (tid & 7) << 2;
  // B staging: 128x32 f16 tile per matrix = 2 rounds x 256 x 16B (f16x8).
  const int brow = tid >> 2;
  const int bc8 = (tid & 3) << 3;

  f32x4 acc[4][4] = {};
  f32x4 accc[4][4] = {};

  const int NT = K / BK;

  float4 rA[4];
  f16x8 rBh[2], rBl[2];

#define LOADR(tt)                                                              \
  do {                                                                         \
    const int k0 = (tt) * BK;                                                  \
    _Pragma("unroll")                                                          \
    for (int r = 0; r < 4; ++r)                                                \
      rA[r] = *reinterpret_cast<const float4*>(A + (m0 + r * 32 + arow) * (long)K + k0 + ac4); \
    _Pragma("unroll")                                                          \
    for (int r = 0; r < 2; ++r) {                                              \
      const long gb = (n0 + r * 64 + brow) * (long)K + k0 + bc8;               \
      rBh[r] = *reinterpret_cast<const f16x8*>(Whi + gb);                      \
      rBl[r] = *reinterpret_cast<const f16x8*>(Wlo + gb);                      \
    }                                                                          \
  } while (0)
#define WRITEB()                                                               \
  do {                                                                         \
    _Pragma("unroll")                                                          \
    for (int r = 0; r < 4; ++r) {                                              \
      f16x4 h4 = {(f16)rA[r].x, (f16)rA[r].y, (f16)rA[r].z, (f16)rA[r].w};     \
      f16x4 l4 = {(f16)((rA[r].x - (float)h4[0]) * 2048.0f),                   \
                  (f16)((rA[r].y - (float)h4[1]) * 2048.0f),                   \
                  (f16)((rA[r].z - (float)h4[2]) * 2048.0f),                   \
                  (f16)((rA[r].w - (float)h4[3]) * 2048.0f)};                  \
      *reinterpret_cast<f16x4*>(&sAh[(r * 32 + arow) * LDSS + ac4]) = h4;      \
      *reinterpret_cast<f16x4*>(&sAl[(r * 32 + arow) * LDSS + ac4]) = l4;      \
    }                                                                          \
    _Pragma("unroll")                                                          \
    for (int r = 0; r < 2; ++r) {                                              \
      *reinterpret_cast<f16x8*>(&sBh[(r * 64 + brow) * LDSS + bc8]) = rBh[r];  \
      *reinterpret_cast<f16x8*>(&sBl[(r * 64 + brow) * LDSS + bc8]) = rBl[r];  \
    }                                                                          \
  } while (0)

  LOADR(0);
  WRITEB();
  __syncthreads();

  for (int t = 0; t < NT; ++t) {
    const bool pf = (t + 1) < NT;
    if (pf) LOADR(t + 1);  // issue early; in flight across the MFMA cluster

    f16x8 ah[4], al[4], bh[4], bl[4];
#pragma unroll
    for (int i = 0; i < 4; ++i) {
      ah[i] = *reinterpret_cast<const f16x8*>(&sAh[(wm + i * 16 + fr) * LDSS + fk]);
      al[i] = *reinterpret_cast<const f16x8*>(&sAl[(wm + i * 16 + fr) * LDSS + fk]);
      bh[i] = *reinterpret_cast<const f16x8*>(&sBh[(wn + i * 16 + fr) * LDSS + fk]);
      bl[i] = *reinterpret_cast<const f16x8*>(&sBl[(wn + i * 16 + fr) * LDSS + fk]);
    }

    __builtin_amdgcn_s_setprio(1);
#pragma unroll
    for (int i = 0; i < 4; ++i)
#pragma unroll
      for (int j = 0; j < 4; ++j) {
        acc[i][j]  = __builtin_amdgcn_mfma_f32_16x16x32_f16(ah[i], bh[j], acc[i][j], 0, 0, 0);
        accc[i][j] = __builtin_amdgcn_mfma_f32_16x16x32_f16(ah[i], bl[j], accc[i][j], 0, 0, 0);
        accc[i][j] = __builtin_amdgcn_mfma_f32_16x16x32_f16(al[i], bh[j], accc[i][j], 0, 0, 0);
      }
    __builtin_amdgcn_s_setprio(0);

    if (pf) {
      __syncthreads();   // all waves done reading tile t (lgkmcnt drained by barrier)
      WRITEB();          // split in regs + ds_write tile t+1 (vmcnt auto-waited)
      __syncthreads();   // publish
    }
  }
#undef LOADR
#undef WRITEB

  // epilogue: C/D layout col = lane&15, row = (lane>>4)*4 + reg
  const int crow = (lane >> 4) * 4;
  const int ccol = lane & 15;
#pragma unroll
  for (int j = 0; j < 4; ++j) {
    int gc = n0 + wn + j * 16 + ccol;
    float bv = bias[gc];
#pragma unroll
    for (int i = 0; i < 4; ++i) {
      long gr = m0 + wm + i * 16 + crow;
#pragma unroll
      for (int r = 0; r < 4; ++r) {
        P[(gr + r) * NCOLS + gc] = acc[i][j][r] + accc[i][j][r] * (1.0f / 2048.0f) + bv;
      }
    }
  }
}

// ---------- BRC scan over one t-chunk: one thread per (b,h) chain ----------
// Y (and HN) pre-offset by the caller to this chunk's base.
__global__ __launch_bounds__(256) void scan_kernel(
    const float* __restrict__ P, const float* __restrict__ hinit,
    float* __restrict__ hstate, int first,
    const float* __restrict__ wc, const float* __restrict__ wa,
    float* __restrict__ Y, float* __restrict__ HN) {
  const int j = blockIdx.x * 256 + threadIdx.x;  // 0..65535
  const int hh = j & (HDIM - 1);
  float h = first ? hinit[j] : hstate[j];
  const float wcv = wc[hh];
  const float wav = wa[hh];
  const float* p = P + (long)(j >> 9) * NCOLS + hh;
  float* y = Y + j;
#pragma unroll 4
  for (int t = 0; t < TCHUNK; ++t) {
    float pc = p[0];
    float pa = p[HDIM];
    float ph = p[2 * HDIM];
    float c = fast_sigmoid(fmaf(wcv, h, pc));
    float a = 1.0f + fast_tanh(fmaf(wav, h, pa));
    h = c * h + (1.0f - c) * fast_tanh(fmaf(a, h, ph));
    *y = h;
    y += BHDIM;
    p += BATCH * NCOLS;
  }
  hstate[j] = h;
  if (HN) HN[j] = h;
}

extern "C" void kernel_launch(void* const* d_in, const int* in_sizes, int n_in,
                              void* d_out, int out_size, void* d_ws, size_t ws_size,
                              hipStream_t stream) {
  const float* x   = (const float*)d_in[0];
  const float* h0  = (const float*)d_in[1];
  const float* Uc0 = (const float*)d_in[2];
  const float* wc0 = (const float*)d_in[3];
  const float* bc0 = (const float*)d_in[4];
  const float* Ua0 = (const float*)d_in[5];
  const float* wa0 = (const float*)d_in[6];
  const float* ba0 = (const float*)d_in[7];
  const float* Uh0 = (const float*)d_in[8];
  const float* bh0 = (const float*)d_in[9];
  const float* Uc1 = (const float*)d_in[10];
  const float* wc1 = (const float*)d_in[11];
  const float* bc1 = (const float*)d_in[12];
  const float* Ua1 = (const float*)d_in[13];
  const float* wa1 = (const float*)d_in[14];
  const float* ba1 = (const float*)d_in[15];
  const float* Uh1 = (const float*)d_in[16];
  const float* bh1 = (const float*)d_in[17];

  if (ws_size < WS_NEEDED) return;

  char* ws = (char*)d_ws;
  float* p32  = (float*)(ws + P32_OFF);
  float* y0   = (float*)(ws + Y0_OFF);
  f16* whi    = (f16*)(ws + WHI_OFF);
  f16* wlo    = (f16*)(ws + WLO_OFF);
  float* bias = (float*)(ws + BIAS_OFF);
  float* hst  = (float*)(ws + HST_OFF);

  float* y1  = (float*)d_out;
  float* hn0 = y1 + (long)SEQ * BHDIM;
  float* hn1 = hn0 + BHDIM;

  const dim3 gemm_grid((CHROWS / 128) * (NCOLS / 128));  // 256*12 = 3072, %8==0

  // ---- prep 0: L0 weight splits + biases ----
  hipLaunchKernelGGL(prep_kernel, dim3(512), dim3(256), 0, stream,
                     Uc0, Ua0, Uh0, whi, wlo, HDIM * INDIM / 4,
                     bc0, ba0, bh0, bias, HDIM / 4);

  // ---- layer 0: chunked GEMM (A = x f32, inline split) + scan ----
  for (int tc = 0; tc < NCH; ++tc) {
    hipLaunchKernelGGL(gemm_split_kernel, gemm_grid, dim3(256), 0, stream,
                       x + (long)tc * CHROWS * INDIM, whi, wlo, bias, p32, INDIM);
    hipLaunchKernelGGL(scan_kernel, dim3(BHDIM / 256), dim3(256), 0, stream,
                       p32, h0, hst, (tc == 0) ? 1 : 0, wc0, wa0,
                       y0 + (long)tc * TCHUNK * BHDIM,
                       (tc == NCH - 1) ? hn0 : (float*)nullptr);
  }

  // ---- prep 1: L1 weight splits + biases ----
  hipLaunchKernelGGL(prep_kernel, dim3(512), dim3(256), 0, stream,
                     Uc1, Ua1, Uh1, whi, wlo, HDIM * HDIM / 4,
                     bc1, ba1, bh1, bias, HDIM / 4);

  // ---- layer 1: chunked GEMM (A = y0 f32, inline split) + scan ----
  for (int tc = 0; tc < NCH; ++tc) {
    hipLaunchKernelGGL(gemm_split_kernel, gemm_grid, dim3(256), 0, stream,
                       y0 + (long)tc * CHROWS * HDIM, whi, wlo, bias, p32, HDIM);
    hipLaunchKernelGGL(scan_kernel, dim3(BHDIM / 256), dim3(256), 0, stream,
                       p32, h0 + BHDIM, hst, (tc == 0) ? 1 : 0, wc1, wa1,
                       y1 + (long)tc * TCHUNK * BHDIM,
                       (tc == NCH - 1) ? hn1 : (float*)nullptr);
  }
}

// Round 16
// 2042.760 us; speedup vs baseline: 6.1228x; 6.1228x over previous
//
#include <hip/hip_runtime.h>
#include <cstdint>
#include <cstddef>

typedef _Float16 f16;
typedef _Float16 f16x4 __attribute__((ext_vector_type(4)));
typedef _Float16 f16x8 __attribute__((ext_vector_type(8)));
typedef float f32x4 __attribute__((ext_vector_type(4)));

// ---------- sizes ----------
#define SEQ 1024
#define BATCH 128
#define INDIM 256
#define HDIM 512
#define MROWS (SEQ * BATCH)          // 131072
#define NCOLS (3 * HDIM)             // 1536
#define BHDIM (BATCH * HDIM)         // 65536
#define TCHUNK 256
#define CHROWS (TCHUNK * BATCH)      // 32768
#define NCH (SEQ / TCHUNK)           // 4

// workspace layout (bytes); total 473,176,064 < 506,730,496 proven available
#define P32_OFF   0ull                         // [32768][1536] f32 = 201,326,592
#define Y0_OFF    201326592ull                 // [131072][512] f32 = 268,435,456
#define WHI_OFF   469762048ull                 // [1536][512] f16   = 1,572,864
#define WLO_OFF   471334912ull                 // [1536][512] f16   = 1,572,864
#define BIAS_OFF  472907776ull                 // [1536] f32        = 6,144
#define HST_OFF   472913920ull                 // [65536] f32       = 262,144
#define WS_NEEDED 473176064ull

// LESSON (r15): __launch_bounds__ min-waves is a COMMAND — forcing 4 waves/EU on a
// ~250-reg kernel spilled accumulators to scratch (VGPR=64, FETCH 3.4GB, 10x slower).
// Dual-accumulator split-GEMM is hard-capped at 2 waves/SIMD. r13 structure restored.

__device__ __forceinline__ float fast_tanh(float x) {
  return 1.0f - 2.0f / (__expf(2.0f * x) + 1.0f);
}
__device__ __forceinline__ float fast_sigmoid(float x) {
  return 1.0f / (1.0f + __expf(-x));
}

__device__ __forceinline__ void split4(const float* __restrict__ in, f16* __restrict__ hi,
                                       f16* __restrict__ lo, int i) {
  float4 v = reinterpret_cast<const float4*>(in)[i];
  f16x4 h4 = {(f16)v.x, (f16)v.y, (f16)v.z, (f16)v.w};
  f16x4 l4 = {(f16)((v.x - (float)h4[0]) * 2048.0f),
              (f16)((v.y - (float)h4[1]) * 2048.0f),
              (f16)((v.z - (float)h4[2]) * 2048.0f),
              (f16)((v.w - (float)h4[3]) * 2048.0f)};
  reinterpret_cast<f16x4*>(hi)[i] = h4;
  reinterpret_cast<f16x4*>(lo)[i] = l4;
}

// ---------- consolidated prep: 3 weight splits + 3 bias copies (one dispatch) ----------
__global__ __launch_bounds__(256) void prep_kernel(
    const float* __restrict__ w0, const float* __restrict__ w1, const float* __restrict__ w2,
    f16* __restrict__ wh, f16* __restrict__ wl, int n4w,
    const float* __restrict__ b0, const float* __restrict__ b1, const float* __restrict__ b2,
    float* __restrict__ bias, int nb4) {
  const int total = 3 * n4w + 3 * nb4;
  const int stride = gridDim.x * blockDim.x;
  for (int i = blockIdx.x * blockDim.x + threadIdx.x; i < total; i += stride) {
    if (i < 3 * n4w) {
      int m = i / n4w;
      int off = i - m * n4w;
      const float* src = (m == 0) ? w0 : ((m == 1) ? w1 : w2);
      split4(src, wh + (long)m * n4w * 4, wl + (long)m * n4w * 4, off);
    } else {
      int k = i - 3 * n4w;
      int m = k / nb4;
      int off = k - m * nb4;
      const float* src = (m == 0) ? b0 : ((m == 1) ? b1 : b2);
      reinterpret_cast<float4*>(bias)[m * nb4 + off] =
          reinterpret_cast<const float4*>(src)[off];
    }
  }
}

// ---------- GEMM: P[CHROWS,1536](f32) = (split(A_f32)).(Whi+Wlo/2048)^T + bias ----------
// r13 (best, 1623us total): T14 reg-staged double-buffered padded LDS, one sync/K-step,
// 16x16x32 MFMA, 4 waves 2x2, 3 MFMA per frag pair, inline A-split during staging.
// At 789 TF MFMA-rate = ~88% of the 2-barrier-128^2 structure ceiling (~900 measured).
__global__ __launch_bounds__(256, 2) void gemm_split_kernel(
    const float* __restrict__ A,
    const f16* __restrict__ Whi, const f16* __restrict__ Wlo,
    const float* __restrict__ bias, float* __restrict__ P, int K) {
  constexpr int BK = 32;
  constexpr int LDSS = BK + 8;  // 40 f16 = 80 B row stride (uniform read banks)
  __shared__ f16 sAh[2][128 * LDSS];
  __shared__ f16 sAl[2][128 * LDSS];
  __shared__ f16 sBh[2][128 * LDSS];
  __shared__ f16 sBl[2][128 * LDSS];

  const int tid = threadIdx.x;
  const int lane = tid & 63;
  const int w = tid >> 6;
  const int wm = (w >> 1) * 64;
  const int wn = (w & 1) * 64;

  // XCD-aware bijective swizzle (gridDim.x = 3072, %8 == 0), n-block fastest
  const int per = gridDim.x >> 3;
  const int logical = (blockIdx.x & 7) * per + (blockIdx.x >> 3);
  const int nb = logical % (NCOLS / 128);
  const int mb = logical / (NCOLS / 128);
  const long m0 = (long)mb * 128;
  const int n0 = nb * 128;

  const int fr = lane & 15;
  const int fk = (lane >> 4) * 8;

  // A staging: 128x32 f32 tile = 4 rounds x 256 threads x 16B (float4); 128B/row segs.
  const int arow = tid >> 3;
  const int ac4 = (tid & 7) << 2;
  // B staging: 128x32 f16 tile per matrix = 2 rounds x 256 x 16B (f16x8).
  const int brow = tid >> 2;
  const int bc8 = (tid & 3) << 3;

  f32x4 acc[4][4] = {};
  f32x4 accc[4][4] = {};

  const int NT = K / BK;

  float4 rA[4];
  f16x8 rBh[2], rBl[2];

#define LOADR(tt)                                                              \
  do {                                                                         \
    const int k0 = (tt) * BK;                                                  \
    _Pragma("unroll")                                                          \
    for (int r = 0; r < 4; ++r)                                                \
      rA[r] = *reinterpret_cast<const float4*>(A + (m0 + r * 32 + arow) * (long)K + k0 + ac4); \
    _Pragma("unroll")                                                          \
    for (int r = 0; r < 2; ++r) {                                              \
      const long gb = (n0 + r * 64 + brow) * (long)K + k0 + bc8;               \
      rBh[r] = *reinterpret_cast<const f16x8*>(Whi + gb);                      \
      rBl[r] = *reinterpret_cast<const f16x8*>(Wlo + gb);                      \
    }                                                                          \
  } while (0)
#define WRITEB(buf)                                                            \
  do {                                                                         \
    _Pragma("unroll")                                                          \
    for (int r = 0; r < 4; ++r) {                                              \
      f16x4 h4 = {(f16)rA[r].x, (f16)rA[r].y, (f16)rA[r].z, (f16)rA[r].w};     \
      f16x4 l4 = {(f16)((rA[r].x - (float)h4[0]) * 2048.0f),                   \
                  (f16)((rA[r].y - (float)h4[1]) * 2048.0f),                   \
                  (f16)((rA[r].z - (float)h4[2]) * 2048.0f),                   \
                  (f16)((rA[r].w - (float)h4[3]) * 2048.0f)};                  \
      *reinterpret_cast<f16x4*>(&sAh[(buf)][(r * 32 + arow) * LDSS + ac4]) = h4; \
      *reinterpret_cast<f16x4*>(&sAl[(buf)][(r * 32 + arow) * LDSS + ac4]) = l4; \
    }                                                                          \
    _Pragma("unroll")                                                          \
    for (int r = 0; r < 2; ++r) {                                              \
      *reinterpret_cast<f16x8*>(&sBh[(buf)][(r * 64 + brow) * LDSS + bc8]) = rBh[r]; \
      *reinterpret_cast<f16x8*>(&sBl[(buf)][(r * 64 + brow) * LDSS + bc8]) = rBl[r]; \
    }                                                                          \
  } while (0)

  LOADR(0);
  WRITEB(0);
  __syncthreads();

  int cur = 0;
  for (int t = 0; t < NT; ++t) {
    const bool pf = (t + 1) < NT;
    if (pf) LOADR(t + 1);  // issue early; vmcnt wait lands after the MFMA cluster

    f16x8 ah[4], al[4], bh[4], bl[4];
#pragma unroll
    for (int i = 0; i < 4; ++i) {
      ah[i] = *reinterpret_cast<const f16x8*>(&sAh[cur][(wm + i * 16 + fr) * LDSS + fk]);
      al[i] = *reinterpret_cast<const f16x8*>(&sAl[cur][(wm + i * 16 + fr) * LDSS + fk]);
      bh[i] = *reinterpret_cast<const f16x8*>(&sBh[cur][(wn + i * 16 + fr) * LDSS + fk]);
      bl[i] = *reinterpret_cast<const f16x8*>(&sBl[cur][(wn + i * 16 + fr) * LDSS + fk]);
    }

    __builtin_amdgcn_s_setprio(1);
#pragma unroll
    for (int i = 0; i < 4; ++i)
#pragma unroll
      for (int j = 0; j < 4; ++j) {
        acc[i][j]  = __builtin_amdgcn_mfma_f32_16x16x32_f16(ah[i], bh[j], acc[i][j], 0, 0, 0);
        accc[i][j] = __builtin_amdgcn_mfma_f32_16x16x32_f16(ah[i], bl[j], accc[i][j], 0, 0, 0);
        accc[i][j] = __builtin_amdgcn_mfma_f32_16x16x32_f16(al[i], bh[j], accc[i][j], 0, 0, 0);
      }
    __builtin_amdgcn_s_setprio(0);

    if (pf) {
      WRITEB(cur ^ 1);   // split in regs + ds_write (vmcnt auto-waited)
      __syncthreads();
      cur ^= 1;
    }
  }
#undef LOADR
#undef WRITEB

  // epilogue: C/D layout col = lane&15, row = (lane>>4)*4 + reg
  const int crow = (lane >> 4) * 4;
  const int ccol = lane & 15;
#pragma unroll
  for (int j = 0; j < 4; ++j) {
    int gc = n0 + wn + j * 16 + ccol;
    float bv = bias[gc];
#pragma unroll
    for (int i = 0; i < 4; ++i) {
      long gr = m0 + wm + i * 16 + crow;
#pragma unroll
      for (int r = 0; r < 4; ++r) {
        P[(gr + r) * NCOLS + gc] = acc[i][j][r] + accc[i][j][r] * (1.0f / 2048.0f) + bv;
      }
    }
  }
}

// ---------- BRC scan over one t-chunk: one thread per (b,h) chain ----------
// Y (and HN) pre-offset by the caller to this chunk's base.
// Scan occupancy is structurally 4 waves/CU (65536 chains); unroll 8 gives ~24
// outstanding address-independent P loads/thread to reach the BW floor at 12.5% occ.
__global__ __launch_bounds__(256) void scan_kernel(
    const float* __restrict__ P, const float* __restrict__ hinit,
    float* __restrict__ hstate, int first,
    const float* __restrict__ wc, const float* __restrict__ wa,
    float* __restrict__ Y, float* __restrict__ HN) {
  const int j = blockIdx.x * 256 + threadIdx.x;  // 0..65535
  const int hh = j & (HDIM - 1);
  float h = first ? hinit[j] : hstate[j];
  const float wcv = wc[hh];
  const float wav = wa[hh];
  const float* p = P + (long)(j >> 9) * NCOLS + hh;
  float* y = Y + j;
#pragma unroll 8
  for (int t = 0; t < TCHUNK; ++t) {
    float pc = p[0];
    float pa = p[HDIM];
    float ph = p[2 * HDIM];
    float c = fast_sigmoid(fmaf(wcv, h, pc));
    float a = 1.0f + fast_tanh(fmaf(wav, h, pa));
    h = c * h + (1.0f - c) * fast_tanh(fmaf(a, h, ph));
    *y = h;
    y += BHDIM;
    p += BATCH * NCOLS;
  }
  hstate[j] = h;
  if (HN) HN[j] = h;
}

extern "C" void kernel_launch(void* const* d_in, const int* in_sizes, int n_in,
                              void* d_out, int out_size, void* d_ws, size_t ws_size,
                              hipStream_t stream) {
  const float* x   = (const float*)d_in[0];
  const float* h0  = (const float*)d_in[1];
  const float* Uc0 = (const float*)d_in[2];
  const float* wc0 = (const float*)d_in[3];
  const float* bc0 = (const float*)d_in[4];
  const float* Ua0 = (const float*)d_in[5];
  const float* wa0 = (const float*)d_in[6];
  const float* ba0 = (const float*)d_in[7];
  const float* Uh0 = (const float*)d_in[8];
  const float* bh0 = (const float*)d_in[9];
  const float* Uc1 = (const float*)d_in[10];
  const float* wc1 = (const float*)d_in[11];
  const float* bc1 = (const float*)d_in[12];
  const float* Ua1 = (const float*)d_in[13];
  const float* wa1 = (const float*)d_in[14];
  const float* ba1 = (const float*)d_in[15];
  const float* Uh1 = (const float*)d_in[16];
  const float* bh1 = (const float*)d_in[17];

  if (ws_size < WS_NEEDED) return;

  char* ws = (char*)d_ws;
  float* p32  = (float*)(ws + P32_OFF);
  float* y0   = (float*)(ws + Y0_OFF);
  f16* whi    = (f16*)(ws + WHI_OFF);
  f16* wlo    = (f16*)(ws + WLO_OFF);
  float* bias = (float*)(ws + BIAS_OFF);
  float* hst  = (float*)(ws + HST_OFF);

  float* y1  = (float*)d_out;
  float* hn0 = y1 + (long)SEQ * BHDIM;
  float* hn1 = hn0 + BHDIM;

  const dim3 gemm_grid((CHROWS / 128) * (NCOLS / 128));  // 256*12 = 3072, %8==0

  // ---- prep 0: L0 weight splits + biases ----
  hipLaunchKernelGGL(prep_kernel, dim3(512), dim3(256), 0, stream,
                     Uc0, Ua0, Uh0, whi, wlo, HDIM * INDIM / 4,
                     bc0, ba0, bh0, bias, HDIM / 4);

  // ---- layer 0: chunked GEMM (A = x f32, inline split) + scan ----
  for (int tc = 0; tc < NCH; ++tc) {
    hipLaunchKernelGGL(gemm_split_kernel, gemm_grid, dim3(256), 0, stream,
                       x + (long)tc * CHROWS * INDIM, whi, wlo, bias, p32, INDIM);
    hipLaunchKernelGGL(scan_kernel, dim3(BHDIM / 256), dim3(256), 0, stream,
                       p32, h0, hst, (tc == 0) ? 1 : 0, wc0, wa0,
                       y0 + (long)tc * TCHUNK * BHDIM,
                       (tc == NCH - 1) ? hn0 : (float*)nullptr);
  }

  // ---- prep 1: L1 weight splits + biases ----
  hipLaunchKernelGGL(prep_kernel, dim3(512), dim3(256), 0, stream,
                     Uc1, Ua1, Uh1, whi, wlo, HDIM * HDIM / 4,
                     bc1, ba1, bh1, bias, HDIM / 4);

  // ---- layer 1: chunked GEMM (A = y0 f32, inline split) + scan ----
  for (int tc = 0; tc < NCH; ++tc) {
    hipLaunchKernelGGL(gemm_split_kernel, gemm_grid, dim3(256), 0, stream,
                       y0 + (long)tc * CHROWS * HDIM, whi, wlo, bias, p32, HDIM);
    hipLaunchKernelGGL(scan_kernel, dim3(BHDIM / 256), dim3(256), 0, stream,
                       p32, h0 + BHDIM, hst, (tc == 0) ? 1 : 0, wc1, wa1,
                       y1 + (long)tc * TCHUNK * BHDIM,
                       (tc == NCH - 1) ? hn1 : (float*)nullptr);
  }
}

// Round 17
// 2028.764 us; speedup vs baseline: 6.1650x; 1.0069x over previous
//
#include <hip/hip_runtime.h>
#include <cstdint>
#include <cstddef>

typedef _Float16 f16;
typedef _Float16 f16x4 __attribute__((ext_vector_type(4)));
typedef _Float16 f16x8 __attribute__((ext_vector_type(8)));
typedef float f32x4 __attribute__((ext_vector_type(4)));

// ---------- sizes ----------
#define SEQ 1024
#define BATCH 128
#define INDIM 256
#define HDIM 512
#define MROWS (SEQ * BATCH)          // 131072
#define NCOLS (3 * HDIM)             // 1536
#define BHDIM (BATCH * HDIM)         // 65536
#define TCHUNK 256
#define CHROWS (TCHUNK * BATCH)      // 32768
#define NCH (SEQ / TCHUNK)           // 4

// workspace layout (bytes); total 473,176,064 < 506,730,496 proven available
#define P32_OFF   0ull                         // [32768][1536] f32 = 201,326,592
#define Y0_OFF    201326592ull                 // [131072][512] f32 = 268,435,456
#define WHI_OFF   469762048ull                 // [1536][512] f16   = 1,572,864
#define WLO_OFF   471334912ull                 // [1536][512] f16   = 1,572,864
#define BIAS_OFF  472907776ull                 // [1536] f32        = 6,144
#define HST_OFF   472913920ull                 // [65536] f32       = 262,144
#define WS_NEEDED 473176064ull

// LESSONS: (r15) __launch_bounds__ min-waves is a COMMAND — forcing 4 waves/EU spilled
// accumulators (VGPR=64, FETCH 3.4GB, 10x). Dual-acc split-GEMM is reg-capped at
// 2 waves/SIMD (124 VGPR + 128 AGPR). (r16) scan unroll 8 regressed +420us (pressure);
// unroll 4 is the sweet spot.

__device__ __forceinline__ float fast_tanh(float x) {
  return 1.0f - 2.0f / (__expf(2.0f * x) + 1.0f);
}
__device__ __forceinline__ float fast_sigmoid(float x) {
  return 1.0f / (1.0f + __expf(-x));
}

__device__ __forceinline__ void split4(const float* __restrict__ in, f16* __restrict__ hi,
                                       f16* __restrict__ lo, int i) {
  float4 v = reinterpret_cast<const float4*>(in)[i];
  f16x4 h4 = {(f16)v.x, (f16)v.y, (f16)v.z, (f16)v.w};
  f16x4 l4 = {(f16)((v.x - (float)h4[0]) * 2048.0f),
              (f16)((v.y - (float)h4[1]) * 2048.0f),
              (f16)((v.z - (float)h4[2]) * 2048.0f),
              (f16)((v.w - (float)h4[3]) * 2048.0f)};
  reinterpret_cast<f16x4*>(hi)[i] = h4;
  reinterpret_cast<f16x4*>(lo)[i] = l4;
}

// ---------- consolidated prep: 3 weight splits + 3 bias copies (one dispatch) ----------
__global__ __launch_bounds__(256) void prep_kernel(
    const float* __restrict__ w0, const float* __restrict__ w1, const float* __restrict__ w2,
    f16* __restrict__ wh, f16* __restrict__ wl, int n4w,
    const float* __restrict__ b0, const float* __restrict__ b1, const float* __restrict__ b2,
    float* __restrict__ bias, int nb4) {
  const int total = 3 * n4w + 3 * nb4;
  const int stride = gridDim.x * blockDim.x;
  for (int i = blockIdx.x * blockDim.x + threadIdx.x; i < total; i += stride) {
    if (i < 3 * n4w) {
      int m = i / n4w;
      int off = i - m * n4w;
      const float* src = (m == 0) ? w0 : ((m == 1) ? w1 : w2);
      split4(src, wh + (long)m * n4w * 4, wl + (long)m * n4w * 4, off);
    } else {
      int k = i - 3 * n4w;
      int m = k / nb4;
      int off = k - m * nb4;
      const float* src = (m == 0) ? b0 : ((m == 1) ? b1 : b2);
      reinterpret_cast<float4*>(bias)[m * nb4 + off] =
          reinterpret_cast<const float4*>(src)[off];
    }
  }
}

// ---------- GEMM: P[CHROWS,1536](f32) = (split(A_f32)).(Whi+Wlo/2048)^T + bias ----------
// r13 structure, minus B LDS staging: B (3MB, L2-resident) fragments are read DIRECTLY
// global->reg each K-step (zero reuse was gained by LDS-staging it; it cost half the
// LDS traffic). A path unchanged: reg-staged inline-split double-buffered padded LDS.
// LDS 80KB -> 40KB; per-CU LDS demand per block-K-step ~1170 -> ~600 cyc.
__global__ __launch_bounds__(256, 2) void gemm_split_kernel(
    const float* __restrict__ A,
    const f16* __restrict__ Whi, const f16* __restrict__ Wlo,
    const float* __restrict__ bias, float* __restrict__ P, int K) {
  constexpr int BK = 32;
  constexpr int LDSS = BK + 8;  // 40 f16 = 80 B row stride (uniform read banks)
  __shared__ f16 sAh[2][128 * LDSS];
  __shared__ f16 sAl[2][128 * LDSS];

  const int tid = threadIdx.x;
  const int lane = tid & 63;
  const int w = tid >> 6;
  const int wm = (w >> 1) * 64;
  const int wn = (w & 1) * 64;

  // XCD-aware bijective swizzle (gridDim.x = 3072, %8 == 0), n-block fastest
  const int per = gridDim.x >> 3;
  const int logical = (blockIdx.x & 7) * per + (blockIdx.x >> 3);
  const int nb = logical % (NCOLS / 128);
  const int mb = logical / (NCOLS / 128);
  const long m0 = (long)mb * 128;
  const int n0 = nb * 128;

  const int fr = lane & 15;
  const int fk = (lane >> 4) * 8;

  // A staging: 128x32 f32 tile = 4 rounds x 256 threads x 16B (float4); 128B/row segs.
  const int arow = tid >> 3;
  const int ac4 = (tid & 7) << 2;

  // B direct-read bases: row = n0 + wn + j*16 + fr, col = k0 + fk.
  const long wBase = (long)(n0 + wn + fr) * K + fk;
  const f16* bH = Whi + wBase;
  const f16* bL = Wlo + wBase;

  f32x4 acc[4][4] = {};
  f32x4 accc[4][4] = {};

  const int NT = K / BK;

  float4 rA[4];

#define LOADA(tt)                                                              \
  do {                                                                         \
    const int k0 = (tt) * BK;                                                  \
    _Pragma("unroll")                                                          \
    for (int r = 0; r < 4; ++r)                                                \
      rA[r] = *reinterpret_cast<const float4*>(A + (m0 + r * 32 + arow) * (long)K + k0 + ac4); \
  } while (0)
#define WRITEA(buf)                                                            \
  do {                                                                         \
    _Pragma("unroll")                                                          \
    for (int r = 0; r < 4; ++r) {                                              \
      f16x4 h4 = {(f16)rA[r].x, (f16)rA[r].y, (f16)rA[r].z, (f16)rA[r].w};     \
      f16x4 l4 = {(f16)((rA[r].x - (float)h4[0]) * 2048.0f),                   \
                  (f16)((rA[r].y - (float)h4[1]) * 2048.0f),                   \
                  (f16)((rA[r].z - (float)h4[2]) * 2048.0f),                   \
                  (f16)((rA[r].w - (float)h4[3]) * 2048.0f)};                  \
      *reinterpret_cast<f16x4*>(&sAh[(buf)][(r * 32 + arow) * LDSS + ac4]) = h4; \
      *reinterpret_cast<f16x4*>(&sAl[(buf)][(r * 32 + arow) * LDSS + ac4]) = l4; \
    }                                                                          \
  } while (0)

  LOADA(0);
  WRITEA(0);
  __syncthreads();

  int cur = 0;
  for (int t = 0; t < NT; ++t) {
    const int k0 = t * BK;
    const bool pf = (t + 1) < NT;

    // B(t) frags direct from global (L2-hot); issued FIRST so their latency hides
    // under the A ds_reads and the co-resident block's compute.
    f16x8 bh[4], bl[4];
#pragma unroll
    for (int j = 0; j < 4; ++j) {
      const long go = (long)j * 16 * K + k0;
      bh[j] = *reinterpret_cast<const f16x8*>(bH + go);
      bl[j] = *reinterpret_cast<const f16x8*>(bL + go);
    }

    if (pf) LOADA(t + 1);  // A(t+1) HBM loads in flight across the MFMA cluster

    f16x8 ah[4], al[4];
#pragma unroll
    for (int i = 0; i < 4; ++i) {
      ah[i] = *reinterpret_cast<const f16x8*>(&sAh[cur][(wm + i * 16 + fr) * LDSS + fk]);
      al[i] = *reinterpret_cast<const f16x8*>(&sAl[cur][(wm + i * 16 + fr) * LDSS + fk]);
    }

    __builtin_amdgcn_s_setprio(1);
#pragma unroll
    for (int i = 0; i < 4; ++i)
#pragma unroll
      for (int j = 0; j < 4; ++j) {
        acc[i][j]  = __builtin_amdgcn_mfma_f32_16x16x32_f16(ah[i], bh[j], acc[i][j], 0, 0, 0);
        accc[i][j] = __builtin_amdgcn_mfma_f32_16x16x32_f16(ah[i], bl[j], accc[i][j], 0, 0, 0);
        accc[i][j] = __builtin_amdgcn_mfma_f32_16x16x32_f16(al[i], bh[j], accc[i][j], 0, 0, 0);
      }
    __builtin_amdgcn_s_setprio(0);

    if (pf) {
      WRITEA(cur ^ 1);   // split in regs + ds_write (vmcnt auto-waited)
      __syncthreads();
      cur ^= 1;
    }
  }
#undef LOADA
#undef WRITEA

  // epilogue: C/D layout col = lane&15, row = (lane>>4)*4 + reg
  const int crow = (lane >> 4) * 4;
  const int ccol = lane & 15;
#pragma unroll
  for (int j = 0; j < 4; ++j) {
    int gc = n0 + wn + j * 16 + ccol;
    float bv = bias[gc];
#pragma unroll
    for (int i = 0; i < 4; ++i) {
      long gr = m0 + wm + i * 16 + crow;
#pragma unroll
      for (int r = 0; r < 4; ++r) {
        P[(gr + r) * NCOLS + gc] = acc[i][j][r] + accc[i][j][r] * (1.0f / 2048.0f) + bv;
      }
    }
  }
}

// ---------- BRC scan over one t-chunk: one thread per (b,h) chain ----------
// Y (and HN) pre-offset by the caller to this chunk's base. unroll 4 (r16: 8 regressed).
__global__ __launch_bounds__(256) void scan_kernel(
    const float* __restrict__ P, const float* __restrict__ hinit,
    float* __restrict__ hstate, int first,
    const float* __restrict__ wc, const float* __restrict__ wa,
    float* __restrict__ Y, float* __restrict__ HN) {
  const int j = blockIdx.x * 256 + threadIdx.x;  // 0..65535
  const int hh = j & (HDIM - 1);
  float h = first ? hinit[j] : hstate[j];
  const float wcv = wc[hh];
  const float wav = wa[hh];
  const float* p = P + (long)(j >> 9) * NCOLS + hh;
  float* y = Y + j;
#pragma unroll 4
  for (int t = 0; t < TCHUNK; ++t) {
    float pc = p[0];
    float pa = p[HDIM];
    float ph = p[2 * HDIM];
    float c = fast_sigmoid(fmaf(wcv, h, pc));
    float a = 1.0f + fast_tanh(fmaf(wav, h, pa));
    h = c * h + (1.0f - c) * fast_tanh(fmaf(a, h, ph));
    *y = h;
    y += BHDIM;
    p += BATCH * NCOLS;
  }
  hstate[j] = h;
  if (HN) HN[j] = h;
}

extern "C" void kernel_launch(void* const* d_in, const int* in_sizes, int n_in,
                              void* d_out, int out_size, void* d_ws, size_t ws_size,
                              hipStream_t stream) {
  const float* x   = (const float*)d_in[0];
  const float* h0  = (const float*)d_in[1];
  const float* Uc0 = (const float*)d_in[2];
  const float* wc0 = (const float*)d_in[3];
  const float* bc0 = (const float*)d_in[4];
  const float* Ua0 = (const float*)d_in[5];
  const float* wa0 = (const float*)d_in[6];
  const float* ba0 = (const float*)d_in[7];
  const float* Uh0 = (const float*)d_in[8];
  const float* bh0 = (const float*)d_in[9];
  const float* Uc1 = (const float*)d_in[10];
  const float* wc1 = (const float*)d_in[11];
  const float* bc1 = (const float*)d_in[12];
  const float* Ua1 = (const float*)d_in[13];
  const float* wa1 = (const float*)d_in[14];
  const float* ba1 = (const float*)d_in[15];
  const float* Uh1 = (const float*)d_in[16];
  const float* bh1 = (const float*)d_in[17];

  if (ws_size < WS_NEEDED) return;

  char* ws = (char*)d_ws;
  float* p32  = (float*)(ws + P32_OFF);
  float* y0   = (float*)(ws + Y0_OFF);
  f16* whi    = (f16*)(ws + WHI_OFF);
  f16* wlo    = (f16*)(ws + WLO_OFF);
  float* bias = (float*)(ws + BIAS_OFF);
  float* hst  = (float*)(ws + HST_OFF);

  float* y1  = (float*)d_out;
  float* hn0 = y1 + (long)SEQ * BHDIM;
  float* hn1 = hn0 + BHDIM;

  const dim3 gemm_grid((CHROWS / 128) * (NCOLS / 128));  // 256*12 = 3072, %8==0

  // ---- prep 0: L0 weight splits + biases ----
  hipLaunchKernelGGL(prep_kernel, dim3(512), dim3(256), 0, stream,
                     Uc0, Ua0, Uh0, whi, wlo, HDIM * INDIM / 4,
                     bc0, ba0, bh0, bias, HDIM / 4);

  // ---- layer 0: chunked GEMM (A = x f32, inline split) + scan ----
  for (int tc = 0; tc < NCH; ++tc) {
    hipLaunchKernelGGL(gemm_split_kernel, gemm_grid, dim3(256), 0, stream,
                       x + (long)tc * CHROWS * INDIM, whi, wlo, bias, p32, INDIM);
    hipLaunchKernelGGL(scan_kernel, dim3(BHDIM / 256), dim3(256), 0, stream,
                       p32, h0, hst, (tc == 0) ? 1 : 0, wc0, wa0,
                       y0 + (long)tc * TCHUNK * BHDIM,
                       (tc == NCH - 1) ? hn0 : (float*)nullptr);
  }

  // ---- prep 1: L1 weight splits + biases ----
  hipLaunchKernelGGL(prep_kernel, dim3(512), dim3(256), 0, stream,
                     Uc1, Ua1, Uh1, whi, wlo, HDIM * HDIM / 4,
                     bc1, ba1, bh1, bias, HDIM / 4);

  // ---- layer 1: chunked GEMM (A = y0 f32, inline split) + scan ----
  for (int tc = 0; tc < NCH; ++tc) {
    hipLaunchKernelGGL(gemm_split_kernel, gemm_grid, dim3(256), 0, stream,
                       y0 + (long)tc * CHROWS * HDIM, whi, wlo, bias, p32, HDIM);
    hipLaunchKernelGGL(scan_kernel, dim3(BHDIM / 256), dim3(256), 0, stream,
                       p32, h0 + BHDIM, hst, (tc == 0) ? 1 : 0, wc1, wa1,
                       y1 + (long)tc * TCHUNK * BHDIM,
                       (tc == NCH - 1) ? hn1 : (float*)nullptr);
  }
}

// Round 19
// 1715.032 us; speedup vs baseline: 7.2928x; 1.1829x over previous
//
#include <hip/hip_runtime.h>
#include <cstdint>
#include <cstddef>

typedef _Float16 f16;
typedef _Float16 f16x4 __attribute__((ext_vector_type(4)));
typedef _Float16 f16x8 __attribute__((ext_vector_type(8)));
typedef float f32x4 __attribute__((ext_vector_type(4)));

#define AS1 __attribute__((address_space(1)))
#define AS3 __attribute__((address_space(3)))

// ---------- sizes ----------
#define SEQ 1024
#define BATCH 128
#define INDIM 256
#define HDIM 512
#define MROWS (SEQ * BATCH)          // 131072
#define NCOLS (3 * HDIM)             // 1536
#define BHDIM (BATCH * HDIM)         // 65536
#define TCHUNK 256
#define CHROWS (TCHUNK * BATCH)      // 32768
#define NCH (SEQ / TCHUNK)           // 4

// workspace layout (bytes); total 473,176,064 < 506,730,496 proven available
#define P32_OFF   0ull                         // [32768][1536] f32 = 201,326,592
#define Y0_OFF    201326592ull                 // [131072][512] f32 = 268,435,456
#define WHI_OFF   469762048ull                 // [1536][512] f16 frag-ordered = 1,572,864
#define WLO_OFF   471334912ull                 // [1536][512] f16 frag-ordered = 1,572,864
#define BIAS_OFF  472907776ull                 // [1536] f32        = 6,144
#define HST_OFF   472913920ull                 // [65536] f32       = 262,144
#define WS_NEEDED 473176064ull

// LESSONS: (r15) __launch_bounds__ min-waves is a COMMAND (spills). (r16) scan unroll
// 8 regressed. (r17) B direct-from-L2 regressed (L2 latency on critical path).
// (r18) gld16 round-r LDS base is r*4096 + w*1024 BYTES (unit u -> byte u*16);
// writing round 1 at +2048 left half of every B tile uninitialized -> NaN.

__device__ __forceinline__ float fast_tanh(float x) {
  return 1.0f - 2.0f / (__expf(2.0f * x) + 1.0f);
}
__device__ __forceinline__ float fast_sigmoid(float x) {
  return 1.0f / (1.0f + __expf(-x));
}

__device__ __forceinline__ void gld16(const void* g, void* l) {
  __builtin_amdgcn_global_load_lds((const AS1 void*)g, (AS3 void*)l, 16, 0, 0);
}

// fragment-order address within a 128x32 f16 tile (f16 units):
// addr(row,k) = (row>>4)*512 + ((k>>3)*16 + (row&15))*8 + (k&7)
// => wave frag read (row=wn+j*16+fr, k=fk..fk+7) = (wng+j)*512 + lane*8 (conflict-free)
// => staging unit u occupies f16 [u*8, u*8+8)  (contiguous global, LDS byte u*16)

// ---------- consolidated prep: B-planes split+fragment-reorder, bias copies ----------
__global__ __launch_bounds__(256) void prep_kernel(
    const float* __restrict__ w0, const float* __restrict__ w1, const float* __restrict__ w2,
    f16* __restrict__ wh, f16* __restrict__ wl, int K,
    const float* __restrict__ b0, const float* __restrict__ b1, const float* __restrict__ b2,
    float* __restrict__ bias, int nb4) {
  const int nuw = HDIM * K / 8;          // units per matrix
  const int total = 3 * nuw + 3 * nb4;
  const int stride = gridDim.x * blockDim.x;
  const int ktiles = K / 32;
  for (int i = blockIdx.x * blockDim.x + threadIdx.x; i < total; i += stride) {
    if (i < 3 * nuw) {
      int m = i / nuw;
      int u = i - m * nuw;
      int n = u / (K / 8);
      int k8 = (u - n * (K / 8)) * 8;
      const float* src = (m == 0) ? w0 : ((m == 1) ? w1 : w2);
      const float* s = src + (long)n * K + k8;
      f16x8 h8, l8;
#pragma unroll
      for (int e = 0; e < 8; ++e) {
        float v = s[e];
        f16 hv = (f16)v;
        h8[e] = hv;
        l8[e] = (f16)((v - (float)hv) * 2048.0f);
      }
      int gn = m * HDIM + n;             // global row 0..1535
      int nblk = gn >> 7, row = gn & 127;
      int kt = k8 >> 5, kk = k8 & 31;
      long dst = ((long)nblk * ktiles + kt) * 4096 +
                 (row >> 4) * 512 + (((kk >> 3) * 16) + (row & 15)) * 8;
      *reinterpret_cast<f16x8*>(wh + dst) = h8;
      *reinterpret_cast<f16x8*>(wl + dst) = l8;
    } else {
      int k = i - 3 * nuw;
      int m = k / nb4;
      int off = k - m * nb4;
      const float* src = (m == 0) ? b0 : ((m == 1) ? b1 : b2);
      reinterpret_cast<float4*>(bias)[m * nb4 + off] =
          reinterpret_cast<const float4*>(src)[off];
    }
  }
}

// ---------- GEMM: P[CHROWS,1536](f32) = (split(A_f32)).(Whi+Wlo/2048)^T + bias ----------
// r13 A-path (reg-staged inline split, padded LDS, T14 dbuf) + B via global_load_lds
// from the fragment-ordered ws layout: no B reg round-trip, no B ds_writes, conflict-
// free wave-linear B frag reads. LDS 72KB -> 2 blocks/CU.
__global__ __launch_bounds__(256, 2) void gemm_split_kernel(
    const float* __restrict__ A,
    const f16* __restrict__ Whi, const f16* __restrict__ Wlo,
    const float* __restrict__ bias, float* __restrict__ P, int K) {
  constexpr int BK = 32;
  constexpr int LDSS = BK + 8;  // A: 40 f16 = 80 B row stride (uniform read banks)
  __shared__ f16 sAh[2][128 * LDSS];
  __shared__ f16 sAl[2][128 * LDSS];
  __shared__ f16 sBh[2][4096];   // fragment-ordered tile
  __shared__ f16 sBl[2][4096];

  const int tid = threadIdx.x;
  const int lane = tid & 63;
  const int w = tid >> 6;
  const int wm = (w >> 1) * 64;
  const int wn = (w & 1) * 64;
  const int wng = wn >> 4;       // B frag group base (0 or 4)

  // XCD-aware bijective swizzle (gridDim.x = 3072, %8 == 0), n-block fastest
  const int per = gridDim.x >> 3;
  const int logical = (blockIdx.x & 7) * per + (blockIdx.x >> 3);
  const int nb = logical % (NCOLS / 128);
  const int mb = logical / (NCOLS / 128);
  const long m0 = (long)mb * 128;
  const int n0 = nb * 128;

  const int fr = lane & 15;
  const int fk = (lane >> 4) * 8;

  // A staging: 128x32 f32 tile = 4 rounds x 256 threads x 16B (float4); 128B/row segs.
  const int arow = tid >> 3;
  const int ac4 = (tid & 7) << 2;

  // B staging: fragment-ordered tile, 2 gld16/thread/plane.
  // round r unit u = r*256 + w*64 + lane; global f16 off = u*8; LDS byte = u*16
  // = r*4096 + w*1024 + lane*16 (HW adds lane*16 to the wave-uniform base).
  const int ktiles = K / 32;
  const f16* bHbase = Whi + (long)nb * ktiles * 4096 + (long)(w * 64 + lane) * 8;
  const f16* bLbase = Wlo + (long)nb * ktiles * 4096 + (long)(w * 64 + lane) * 8;
  const int ldswB = w * 1024;    // bytes, round-0 wave base

  f32x4 acc[4][4] = {};
  f32x4 accc[4][4] = {};

  const int NT = K / BK;

  float4 rA[4];

#define LOADA(tt)                                                              \
  do {                                                                         \
    const int k0 = (tt) * BK;                                                  \
    _Pragma("unroll")                                                          \
    for (int r = 0; r < 4; ++r)                                                \
      rA[r] = *reinterpret_cast<const float4*>(A + (m0 + r * 32 + arow) * (long)K + k0 + ac4); \
  } while (0)
#define WRITEA(buf)                                                            \
  do {                                                                         \
    _Pragma("unroll")                                                          \
    for (int r = 0; r < 4; ++r) {                                              \
      f16x4 h4 = {(f16)rA[r].x, (f16)rA[r].y, (f16)rA[r].z, (f16)rA[r].w};     \
      f16x4 l4 = {(f16)((rA[r].x - (float)h4[0]) * 2048.0f),                   \
                  (f16)((rA[r].y - (float)h4[1]) * 2048.0f),                   \
                  (f16)((rA[r].z - (float)h4[2]) * 2048.0f),                   \
                  (f16)((rA[r].w - (float)h4[3]) * 2048.0f)};                  \
      *reinterpret_cast<f16x4*>(&sAh[(buf)][(r * 32 + arow) * LDSS + ac4]) = h4; \
      *reinterpret_cast<f16x4*>(&sAl[(buf)][(r * 32 + arow) * LDSS + ac4]) = l4; \
    }                                                                          \
  } while (0)
#define STAGEB(buf, tt)                                                        \
  do {                                                                         \
    const long tb = (long)(tt) * 4096;                                         \
    gld16(bHbase + tb,        (char*)&sBh[(buf)][0] + ldswB);                  \
    gld16(bHbase + tb + 2048, (char*)&sBh[(buf)][0] + 4096 + ldswB);           \
    gld16(bLbase + tb,        (char*)&sBl[(buf)][0] + ldswB);                  \
    gld16(bLbase + tb + 2048, (char*)&sBl[(buf)][0] + 4096 + ldswB);           \
  } while (0)

  LOADA(0);
  STAGEB(0, 0);
  WRITEA(0);
  __syncthreads();   // drains vmcnt (gld16) + lgkm: tile 0 ready

  int cur = 0;
  for (int t = 0; t < NT; ++t) {
    const bool pf = (t + 1) < NT;
    if (pf) {
      STAGEB(cur ^ 1, t + 1);  // async direct-to-LDS; drained by end-of-step barrier
      LOADA(t + 1);            // A regs in flight across the MFMA cluster
    }

    f16x8 ah[4], al[4], bh[4], bl[4];
#pragma unroll
    for (int i = 0; i < 4; ++i) {
      ah[i] = *reinterpret_cast<const f16x8*>(&sAh[cur][(wm + i * 16 + fr) * LDSS + fk]);
      al[i] = *reinterpret_cast<const f16x8*>(&sAl[cur][(wm + i * 16 + fr) * LDSS + fk]);
      bh[i] = *reinterpret_cast<const f16x8*>(&sBh[cur][(wng + i) * 512 + lane * 8]);
      bl[i] = *reinterpret_cast<const f16x8*>(&sBl[cur][(wng + i) * 512 + lane * 8]);
    }

    __builtin_amdgcn_s_setprio(1);
#pragma unroll
    for (int i = 0; i < 4; ++i)
#pragma unroll
      for (int j = 0; j < 4; ++j) {
        acc[i][j]  = __builtin_amdgcn_mfma_f32_16x16x32_f16(ah[i], bh[j], acc[i][j], 0, 0, 0);
        accc[i][j] = __builtin_amdgcn_mfma_f32_16x16x32_f16(ah[i], bl[j], accc[i][j], 0, 0, 0);
        accc[i][j] = __builtin_amdgcn_mfma_f32_16x16x32_f16(al[i], bh[j], accc[i][j], 0, 0, 0);
      }
    __builtin_amdgcn_s_setprio(0);

    if (pf) {
      WRITEA(cur ^ 1);   // split in regs + ds_write (vmcnt auto-waited)
      __syncthreads();   // drains gld16 + ds_writes; buffers flip
      cur ^= 1;
    }
  }
#undef LOADA
#undef WRITEA
#undef STAGEB

  // epilogue: C/D layout col = lane&15, row = (lane>>4)*4 + reg
  const int crow = (lane >> 4) * 4;
  const int ccol = lane & 15;
#pragma unroll
  for (int j = 0; j < 4; ++j) {
    int gc = n0 + wn + j * 16 + ccol;
    float bv = bias[gc];
#pragma unroll
    for (int i = 0; i < 4; ++i) {
      long gr = m0 + wm + i * 16 + crow;
#pragma unroll
      for (int r = 0; r < 4; ++r) {
        P[(gr + r) * NCOLS + gc] = acc[i][j][r] + accc[i][j][r] * (1.0f / 2048.0f) + bv;
      }
    }
  }
}

// ---------- BRC scan over one t-chunk: one thread per (b,h) chain ----------
// Y (and HN) pre-offset by the caller to this chunk's base. unroll 4 (r16: 8 regressed).
__global__ __launch_bounds__(256) void scan_kernel(
    const float* __restrict__ P, const float* __restrict__ hinit,
    float* __restrict__ hstate, int first,
    const float* __restrict__ wc, const float* __restrict__ wa,
    float* __restrict__ Y, float* __restrict__ HN) {
  const int j = blockIdx.x * 256 + threadIdx.x;  // 0..65535
  const int hh = j & (HDIM - 1);
  float h = first ? hinit[j] : hstate[j];
  const float wcv = wc[hh];
  const float wav = wa[hh];
  const float* p = P + (long)(j >> 9) * NCOLS + hh;
  float* y = Y + j;
#pragma unroll 4
  for (int t = 0; t < TCHUNK; ++t) {
    float pc = p[0];
    float pa = p[HDIM];
    float ph = p[2 * HDIM];
    float c = fast_sigmoid(fmaf(wcv, h, pc));
    float a = 1.0f + fast_tanh(fmaf(wav, h, pa));
    h = c * h + (1.0f - c) * fast_tanh(fmaf(a, h, ph));
    *y = h;
    y += BHDIM;
    p += BATCH * NCOLS;
  }
  hstate[j] = h;
  if (HN) HN[j] = h;
}

extern "C" void kernel_launch(void* const* d_in, const int* in_sizes, int n_in,
                              void* d_out, int out_size, void* d_ws, size_t ws_size,
                              hipStream_t stream) {
  const float* x   = (const float*)d_in[0];
  const float* h0  = (const float*)d_in[1];
  const float* Uc0 = (const float*)d_in[2];
  const float* wc0 = (const float*)d_in[3];
  const float* bc0 = (const float*)d_in[4];
  const float* Ua0 = (const float*)d_in[5];
  const float* wa0 = (const float*)d_in[6];
  const float* ba0 = (const float*)d_in[7];
  const float* Uh0 = (const float*)d_in[8];
  const float* bh0 = (const float*)d_in[9];
  const float* Uc1 = (const float*)d_in[10];
  const float* wc1 = (const float*)d_in[11];
  const float* bc1 = (const float*)d_in[12];
  const float* Ua1 = (const float*)d_in[13];
  const float* wa1 = (const float*)d_in[14];
  const float* ba1 = (const float*)d_in[15];
  const float* Uh1 = (const float*)d_in[16];
  const float* bh1 = (const float*)d_in[17];

  if (ws_size < WS_NEEDED) return;

  char* ws = (char*)d_ws;
  float* p32  = (float*)(ws + P32_OFF);
  float* y0   = (float*)(ws + Y0_OFF);
  f16* whi    = (f16*)(ws + WHI_OFF);
  f16* wlo    = (f16*)(ws + WLO_OFF);
  float* bias = (float*)(ws + BIAS_OFF);
  float* hst  = (float*)(ws + HST_OFF);

  float* y1  = (float*)d_out;
  float* hn0 = y1 + (long)SEQ * BHDIM;
  float* hn1 = hn0 + BHDIM;

  const dim3 gemm_grid((CHROWS / 128) * (NCOLS / 128));  // 256*12 = 3072, %8==0

  // ---- prep 0: L0 weight split + fragment reorder + biases ----
  hipLaunchKernelGGL(prep_kernel, dim3(512), dim3(256), 0, stream,
                     Uc0, Ua0, Uh0, whi, wlo, INDIM,
                     bc0, ba0, bh0, bias, HDIM / 4);

  // ---- layer 0: chunked GEMM (A = x f32, inline split) + scan ----
  for (int tc = 0; tc < NCH; ++tc) {
    hipLaunchKernelGGL(gemm_split_kernel, gemm_grid, dim3(256), 0, stream,
                       x + (long)tc * CHROWS * INDIM, whi, wlo, bias, p32, INDIM);
    hipLaunchKernelGGL(scan_kernel, dim3(BHDIM / 256), dim3(256), 0, stream,
                       p32, h0, hst, (tc == 0) ? 1 : 0, wc0, wa0,
                       y0 + (long)tc * TCHUNK * BHDIM,
                       (tc == NCH - 1) ? hn0 : (float*)nullptr);
  }

  // ---- prep 1: L1 weight split + fragment reorder + biases ----
  hipLaunchKernelGGL(prep_kernel, dim3(512), dim3(256), 0, stream,
                     Uc1, Ua1, Uh1, whi, wlo, HDIM,
                     bc1, ba1, bh1, bias, HDIM / 4);

  // ---- layer 1: chunked GEMM (A = y0 f32, inline split) + scan ----
  for (int tc = 0; tc < NCH; ++tc) {
    hipLaunchKernelGGL(gemm_split_kernel, gemm_grid, dim3(256), 0, stream,
                       y0 + (long)tc * CHROWS * HDIM, whi, wlo, bias, p32, HDIM);
    hipLaunchKernelGGL(scan_kernel, dim3(BHDIM / 256), dim3(256), 0, stream,
                       p32, h0 + BHDIM, hst, (tc == 0) ? 1 : 0, wc1, wa1,
                       y1 + (long)tc * TCHUNK * BHDIM,
                       (tc == NCH - 1) ? hn1 : (float*)nullptr);
  }
}

// Round 20
// 1601.707 us; speedup vs baseline: 7.8087x; 1.0708x over previous
//
#include <hip/hip_runtime.h>
#include <cstdint>
#include <cstddef>

typedef _Float16 f16;
typedef _Float16 f16x4 __attribute__((ext_vector_type(4)));
typedef _Float16 f16x8 __attribute__((ext_vector_type(8)));
typedef float f32x4 __attribute__((ext_vector_type(4)));

// ---------- sizes ----------
#define SEQ 1024
#define BATCH 128
#define INDIM 256
#define HDIM 512
#define MROWS (SEQ * BATCH)          // 131072
#define NCOLS (3 * HDIM)             // 1536
#define BHDIM (BATCH * HDIM)         // 65536
#define TCHUNK 256
#define CHROWS (TCHUNK * BATCH)      // 32768
#define NCH (SEQ / TCHUNK)           // 4

// workspace layout (bytes); total 473,176,064 < 506,730,496 proven available
#define P32_OFF   0ull                         // [32768][1536] f32 = 201,326,592
#define Y0_OFF    201326592ull                 // [131072][512] f32 = 268,435,456
#define WHI_OFF   469762048ull                 // [1536][512] f16   = 1,572,864
#define WLO_OFF   471334912ull                 // [1536][512] f16   = 1,572,864
#define BIAS_OFF  472907776ull                 // [1536] f32        = 6,144
#define HST_OFF   472913920ull                 // [65536] f32       = 262,144
#define WS_NEEDED 473176064ull

// LESSONS (r14-r19, all vs r13=1623us): frag-ordered LDS scattered A's global reads
// (r14); __launch_bounds__ min-waves is a COMMAND -> spills (r15); scan unroll 8
// regressed (r16); B direct-from-L2 put L2 latency on the critical path (r17);
// B via global_load_lds correct but slower than reg-staged (r19). Dual-accumulator
// split-GEMM is register-capped at 2 waves/SIMD; that locks out the 8-phase class.
// r13 = structural optimum of the 2-barrier 128^2 class for this arithmetic.
// This round: exact r13 minus s_setprio (m190: setprio is ~-1.5% on this class).

__device__ __forceinline__ float fast_tanh(float x) {
  return 1.0f - 2.0f / (__expf(2.0f * x) + 1.0f);
}
__device__ __forceinline__ float fast_sigmoid(float x) {
  return 1.0f / (1.0f + __expf(-x));
}

__device__ __forceinline__ void split4(const float* __restrict__ in, f16* __restrict__ hi,
                                       f16* __restrict__ lo, int i) {
  float4 v = reinterpret_cast<const float4*>(in)[i];
  f16x4 h4 = {(f16)v.x, (f16)v.y, (f16)v.z, (f16)v.w};
  f16x4 l4 = {(f16)((v.x - (float)h4[0]) * 2048.0f),
              (f16)((v.y - (float)h4[1]) * 2048.0f),
              (f16)((v.z - (float)h4[2]) * 2048.0f),
              (f16)((v.w - (float)h4[3]) * 2048.0f)};
  reinterpret_cast<f16x4*>(hi)[i] = h4;
  reinterpret_cast<f16x4*>(lo)[i] = l4;
}

// ---------- consolidated prep: 3 weight splits + 3 bias copies (one dispatch) ----------
__global__ __launch_bounds__(256) void prep_kernel(
    const float* __restrict__ w0, const float* __restrict__ w1, const float* __restrict__ w2,
    f16* __restrict__ wh, f16* __restrict__ wl, int n4w,
    const float* __restrict__ b0, const float* __restrict__ b1, const float* __restrict__ b2,
    float* __restrict__ bias, int nb4) {
  const int total = 3 * n4w + 3 * nb4;
  const int stride = gridDim.x * blockDim.x;
  for (int i = blockIdx.x * blockDim.x + threadIdx.x; i < total; i += stride) {
    if (i < 3 * n4w) {
      int m = i / n4w;
      int off = i - m * n4w;
      const float* src = (m == 0) ? w0 : ((m == 1) ? w1 : w2);
      split4(src, wh + (long)m * n4w * 4, wl + (long)m * n4w * 4, off);
    } else {
      int k = i - 3 * n4w;
      int m = k / nb4;
      int off = k - m * nb4;
      const float* src = (m == 0) ? b0 : ((m == 1) ? b1 : b2);
      reinterpret_cast<float4*>(bias)[m * nb4 + off] =
          reinterpret_cast<const float4*>(src)[off];
    }
  }
}

// ---------- GEMM: P[CHROWS,1536](f32) = (split(A_f32)).(Whi+Wlo/2048)^T + bias ----------
// r13 (best): T14 reg-staged double-buffered padded LDS, one sync/K-step, 16x16x32
// MFMA, 4 waves 2x2, 3 MFMA per frag pair, inline A-split during staging.
__global__ __launch_bounds__(256, 2) void gemm_split_kernel(
    const float* __restrict__ A,
    const f16* __restrict__ Whi, const f16* __restrict__ Wlo,
    const float* __restrict__ bias, float* __restrict__ P, int K) {
  constexpr int BK = 32;
  constexpr int LDSS = BK + 8;  // 40 f16 = 80 B row stride (uniform read banks)
  __shared__ f16 sAh[2][128 * LDSS];
  __shared__ f16 sAl[2][128 * LDSS];
  __shared__ f16 sBh[2][128 * LDSS];
  __shared__ f16 sBl[2][128 * LDSS];

  const int tid = threadIdx.x;
  const int lane = tid & 63;
  const int w = tid >> 6;
  const int wm = (w >> 1) * 64;
  const int wn = (w & 1) * 64;

  // XCD-aware bijective swizzle (gridDim.x = 3072, %8 == 0), n-block fastest
  const int per = gridDim.x >> 3;
  const int logical = (blockIdx.x & 7) * per + (blockIdx.x >> 3);
  const int nb = logical % (NCOLS / 128);
  const int mb = logical / (NCOLS / 128);
  const long m0 = (long)mb * 128;
  const int n0 = nb * 128;

  const int fr = lane & 15;
  const int fk = (lane >> 4) * 8;

  // A staging: 128x32 f32 tile = 4 rounds x 256 threads x 16B (float4); 128B/row segs.
  const int arow = tid >> 3;
  const int ac4 = (tid & 7) << 2;
  // B staging: 128x32 f16 tile per matrix = 2 rounds x 256 x 16B (f16x8).
  const int brow = tid >> 2;
  const int bc8 = (tid & 3) << 3;

  f32x4 acc[4][4] = {};
  f32x4 accc[4][4] = {};

  const int NT = K / BK;

  float4 rA[4];
  f16x8 rBh[2], rBl[2];

#define LOADR(tt)                                                              \
  do {                                                                         \
    const int k0 = (tt) * BK;                                                  \
    _Pragma("unroll")                                                          \
    for (int r = 0; r < 4; ++r)                                                \
      rA[r] = *reinterpret_cast<const float4*>(A + (m0 + r * 32 + arow) * (long)K + k0 + ac4); \
    _Pragma("unroll")                                                          \
    for (int r = 0; r < 2; ++r) {                                              \
      const long gb = (n0 + r * 64 + brow) * (long)K + k0 + bc8;               \
      rBh[r] = *reinterpret_cast<const f16x8*>(Whi + gb);                      \
      rBl[r] = *reinterpret_cast<const f16x8*>(Wlo + gb);                      \
    }                                                                          \
  } while (0)
#define WRITEB(buf)                                                            \
  do {                                                                         \
    _Pragma("unroll")                                                          \
    for (int r = 0; r < 4; ++r) {                                              \
      f16x4 h4 = {(f16)rA[r].x, (f16)rA[r].y, (f16)rA[r].z, (f16)rA[r].w};     \
      f16x4 l4 = {(f16)((rA[r].x - (float)h4[0]) * 2048.0f),                   \
                  (f16)((rA[r].y - (float)h4[1]) * 2048.0f),                   \
                  (f16)((rA[r].z - (float)h4[2]) * 2048.0f),                   \
                  (f16)((rA[r].w - (float)h4[3]) * 2048.0f)};                  \
      *reinterpret_cast<f16x4*>(&sAh[(buf)][(r * 32 + arow) * LDSS + ac4]) = h4; \
      *reinterpret_cast<f16x4*>(&sAl[(buf)][(r * 32 + arow) * LDSS + ac4]) = l4; \
    }                                                                          \
    _Pragma("unroll")                                                          \
    for (int r = 0; r < 2; ++r) {                                              \
      *reinterpret_cast<f16x8*>(&sBh[(buf)][(r * 64 + brow) * LDSS + bc8]) = rBh[r]; \
      *reinterpret_cast<f16x8*>(&sBl[(buf)][(r * 64 + brow) * LDSS + bc8]) = rBl[r]; \
    }                                                                          \
  } while (0)

  LOADR(0);
  WRITEB(0);
  __syncthreads();

  int cur = 0;
  for (int t = 0; t < NT; ++t) {
    const bool pf = (t + 1) < NT;
    if (pf) LOADR(t + 1);  // issue early; vmcnt wait lands after the MFMA cluster

    f16x8 ah[4], al[4], bh[4], bl[4];
#pragma unroll
    for (int i = 0; i < 4; ++i) {
      ah[i] = *reinterpret_cast<const f16x8*>(&sAh[cur][(wm + i * 16 + fr) * LDSS + fk]);
      al[i] = *reinterpret_cast<const f16x8*>(&sAl[cur][(wm + i * 16 + fr) * LDSS + fk]);
      bh[i] = *reinterpret_cast<const f16x8*>(&sBh[cur][(wn + i * 16 + fr) * LDSS + fk]);
      bl[i] = *reinterpret_cast<const f16x8*>(&sBl[cur][(wn + i * 16 + fr) * LDSS + fk]);
    }

#pragma unroll
    for (int i = 0; i < 4; ++i)
#pragma unroll
      for (int j = 0; j < 4; ++j) {
        acc[i][j]  = __builtin_amdgcn_mfma_f32_16x16x32_f16(ah[i], bh[j], acc[i][j], 0, 0, 0);
        accc[i][j] = __builtin_amdgcn_mfma_f32_16x16x32_f16(ah[i], bl[j], accc[i][j], 0, 0, 0);
        accc[i][j] = __builtin_amdgcn_mfma_f32_16x16x32_f16(al[i], bh[j], accc[i][j], 0, 0, 0);
      }

    if (pf) {
      WRITEB(cur ^ 1);   // split in regs + ds_write (vmcnt auto-waited)
      __syncthreads();
      cur ^= 1;
    }
  }
#undef LOADR
#undef WRITEB

  // epilogue: C/D layout col = lane&15, row = (lane>>4)*4 + reg
  const int crow = (lane >> 4) * 4;
  const int ccol = lane & 15;
#pragma unroll
  for (int j = 0; j < 4; ++j) {
    int gc = n0 + wn + j * 16 + ccol;
    float bv = bias[gc];
#pragma unroll
    for (int i = 0; i < 4; ++i) {
      long gr = m0 + wm + i * 16 + crow;
#pragma unroll
      for (int r = 0; r < 4; ++r) {
        P[(gr + r) * NCOLS + gc] = acc[i][j][r] + accc[i][j][r] * (1.0f / 2048.0f) + bv;
      }
    }
  }
}

// ---------- BRC scan over one t-chunk: one thread per (b,h) chain ----------
// Y (and HN) pre-offset by the caller to this chunk's base. unroll 4 (r16: 8 regressed).
__global__ __launch_bounds__(256) void scan_kernel(
    const float* __restrict__ P, const float* __restrict__ hinit,
    float* __restrict__ hstate, int first,
    const float* __restrict__ wc, const float* __restrict__ wa,
    float* __restrict__ Y, float* __restrict__ HN) {
  const int j = blockIdx.x * 256 + threadIdx.x;  // 0..65535
  const int hh = j & (HDIM - 1);
  float h = first ? hinit[j] : hstate[j];
  const float wcv = wc[hh];
  const float wav = wa[hh];
  const float* p = P + (long)(j >> 9) * NCOLS + hh;
  float* y = Y + j;
#pragma unroll 4
  for (int t = 0; t < TCHUNK; ++t) {
    float pc = p[0];
    float pa = p[HDIM];
    float ph = p[2 * HDIM];
    float c = fast_sigmoid(fmaf(wcv, h, pc));
    float a = 1.0f + fast_tanh(fmaf(wav, h, pa));
    h = c * h + (1.0f - c) * fast_tanh(fmaf(a, h, ph));
    *y = h;
    y += BHDIM;
    p += BATCH * NCOLS;
  }
  hstate[j] = h;
  if (HN) HN[j] = h;
}

extern "C" void kernel_launch(void* const* d_in, const int* in_sizes, int n_in,
                              void* d_out, int out_size, void* d_ws, size_t ws_size,
                              hipStream_t stream) {
  const float* x   = (const float*)d_in[0];
  const float* h0  = (const float*)d_in[1];
  const float* Uc0 = (const float*)d_in[2];
  const float* wc0 = (const float*)d_in[3];
  const float* bc0 = (const float*)d_in[4];
  const float* Ua0 = (const float*)d_in[5];
  const float* wa0 = (const float*)d_in[6];
  const float* ba0 = (const float*)d_in[7];
  const float* Uh0 = (const float*)d_in[8];
  const float* bh0 = (const float*)d_in[9];
  const float* Uc1 = (const float*)d_in[10];
  const float* wc1 = (const float*)d_in[11];
  const float* bc1 = (const float*)d_in[12];
  const float* Ua1 = (const float*)d_in[13];
  const float* wa1 = (const float*)d_in[14];
  const float* ba1 = (const float*)d_in[15];
  const float* Uh1 = (const float*)d_in[16];
  const float* bh1 = (const float*)d_in[17];

  if (ws_size < WS_NEEDED) return;

  char* ws = (char*)d_ws;
  float* p32  = (float*)(ws + P32_OFF);
  float* y0   = (float*)(ws + Y0_OFF);
  f16* whi    = (f16*)(ws + WHI_OFF);
  f16* wlo    = (f16*)(ws + WLO_OFF);
  float* bias = (float*)(ws + BIAS_OFF);
  float* hst  = (float*)(ws + HST_OFF);

  float* y1  = (float*)d_out;
  float* hn0 = y1 + (long)SEQ * BHDIM;
  float* hn1 = hn0 + BHDIM;

  const dim3 gemm_grid((CHROWS / 128) * (NCOLS / 128));  // 256*12 = 3072, %8==0

  // ---- prep 0: L0 weight splits + biases ----
  hipLaunchKernelGGL(prep_kernel, dim3(512), dim3(256), 0, stream,
                     Uc0, Ua0, Uh0, whi, wlo, HDIM * INDIM / 4,
                     bc0, ba0, bh0, bias, HDIM / 4);

  // ---- layer 0: chunked GEMM (A = x f32, inline split) + scan ----
  for (int tc = 0; tc < NCH; ++tc) {
    hipLaunchKernelGGL(gemm_split_kernel, gemm_grid, dim3(256), 0, stream,
                       x + (long)tc * CHROWS * INDIM, whi, wlo, bias, p32, INDIM);
    hipLaunchKernelGGL(scan_kernel, dim3(BHDIM / 256), dim3(256), 0, stream,
                       p32, h0, hst, (tc == 0) ? 1 : 0, wc0, wa0,
                       y0 + (long)tc * TCHUNK * BHDIM,
                       (tc == NCH - 1) ? hn0 : (float*)nullptr);
  }

  // ---- prep 1: L1 weight splits + biases ----
  hipLaunchKernelGGL(prep_kernel, dim3(512), dim3(256), 0, stream,
                     Uc1, Ua1, Uh1, whi, wlo, HDIM * HDIM / 4,
                     bc1, ba1, bh1, bias, HDIM / 4);

  // ---- layer 1: chunked GEMM (A = y0 f32, inline split) + scan ----
  for (int tc = 0; tc < NCH; ++tc) {
    hipLaunchKernelGGL(gemm_split_kernel, gemm_grid, dim3(256), 0, stream,
                       y0 + (long)tc * CHROWS * HDIM, whi, wlo, bias, p32, HDIM);
    hipLaunchKernelGGL(scan_kernel, dim3(BHDIM / 256), dim3(256), 0, stream,
                       p32, h0 + BHDIM, hst, (tc == 0) ? 1 : 0, wc1, wa1,
                       y1 + (long)tc * TCHUNK * BHDIM,
                       (tc == NCH - 1) ? hn1 : (float*)nullptr);
  }
}